// Round 2
// baseline (353.948 us; speedup 1.0000x reference)
//
#include <hip/hip_runtime.h>
#include <hip/hip_bf16.h>

typedef short short8 __attribute__((ext_vector_type(8)));
typedef float floatx4 __attribute__((ext_vector_type(4)));

#define AS_G __attribute__((address_space(1)))
#define AS_L __attribute__((address_space(3)))

__device__ __forceinline__ unsigned short f2bf(float f) {
    union { float f; unsigned u; } v; v.f = f;
    unsigned r = (v.u + 0x7FFF + ((v.u >> 16) & 1)) >> 16;
    return (unsigned short)r;
}

// ---- MX decoders (match reference bit-for-bit; all results exact in bf16) ----
__device__ __forceinline__ float dec4(int c) {          // E2M1
    float s = (c & 8) ? -1.f : 1.f;
    int e = (c >> 1) & 3, m = c & 1;
    float mag = e ? ldexpf(1.f + 0.5f * (float)m, e - 1) : 0.5f * (float)m;
    return s * mag;
}
__device__ __forceinline__ float dec6(int c) {          // E3M2, bias 3
    float s = (c & 32) ? -1.f : 1.f;
    int e = (c >> 2) & 7, m = c & 3;
    float mag = e ? ldexpf(1.f + 0.25f * (float)m, e - 3) : 0.0625f * (float)m;
    return s * mag;
}
__device__ __forceinline__ float dec8(int c) {          // E4M3, bias 7 (NaN code -> 480, same as ref)
    float s = (c & 128) ? -1.f : 1.f;
    int e = (c >> 3) & 15, m = c & 7;
    float mag = e ? ldexpf(1.f + 0.125f * (float)m, e - 7) : ldexpf(0.125f * (float)m, -6);
    return s * mag;
}

// One row-side dequant: layout [rows, 4096] bf16, K order = [3072 fp4 | 768 fp6 | 256 fp8].
// Thread t handles 8 consecutive k (one 16B store). kb = t & 511.
__global__ __launch_bounds__(256) void dequant_kernel(
    const int* __restrict__ Pn, const int* __restrict__ Ps, const int* __restrict__ Po,
    const int* __restrict__ Sn, const int* __restrict__ Ss, const int* __restrict__ So,
    unsigned short* __restrict__ out, int rows)
{
    int t = blockIdx.x * 256 + threadIdx.x;
    if (t >= rows * 512) return;
    int m = t >> 9;
    int kb = t & 511;
    float v[8];
    int sf;
    if (kb < 384) {                       // fp4: 8 vals = 4 bytes (4 int32) = one int4
        const int4* p = (const int4*)(Pn + (size_t)m * 1536);
        int4 b = p[kb];
        sf = Sn[m * 96 + (kb >> 2)];
        int bs[4] = { b.x, b.y, b.z, b.w };
        #pragma unroll
        for (int i = 0; i < 4; i++) {
            int c = bs[i] & 0xFF;
            v[2 * i]     = dec4(c & 15);
            v[2 * i + 1] = dec4((c >> 4) & 15);
        }
    } else if (kb < 480) {                // fp6: 8 vals = 6 bytes (little-endian 6-bit pack)
        int g = kb - 384;
        const int* p = Ps + (size_t)m * 576 + g * 6;
        sf = Ss[m * 24 + (g >> 2)];
        int b0 = p[0] & 255, b1 = p[1] & 255, b2 = p[2] & 255;
        int b3 = p[3] & 255, b4 = p[4] & 255, b5 = p[5] & 255;
        v[0] = dec6(b0 & 63);
        v[1] = dec6(((b0 >> 6) & 3) | ((b1 & 15) << 2));
        v[2] = dec6(((b1 >> 4) & 15) | ((b2 & 3) << 4));
        v[3] = dec6((b2 >> 2) & 63);
        v[4] = dec6(b3 & 63);
        v[5] = dec6(((b3 >> 6) & 3) | ((b4 & 15) << 2));
        v[6] = dec6(((b4 >> 4) & 15) | ((b5 & 3) << 4));
        v[7] = dec6((b5 >> 2) & 63);
    } else {                              // fp8: 8 vals = 8 int32 = two int4
        int g = kb - 480;
        const int4* p = (const int4*)(Po + (size_t)m * 256 + g * 8);
        int4 c0 = p[0], c1 = p[1];
        sf = So[m * 8 + (g >> 2)];
        int cs[8] = { c0.x, c0.y, c0.z, c0.w, c1.x, c1.y, c1.z, c1.w };
        #pragma unroll
        for (int i = 0; i < 8; i++) v[i] = dec8(cs[i] & 255);
    }
    int e = sf - 127;
    uint4 o;
    unsigned* po = (unsigned*)&o;
    #pragma unroll
    for (int i = 0; i < 4; i++) {
        unsigned lo = f2bf(ldexpf(v[2 * i], e));
        unsigned hi = f2bf(ldexpf(v[2 * i + 1], e));
        po[i] = lo | (hi << 16);
    }
    ((uint4*)(out + (size_t)m * 4096))[kb] = o;
}

// ---- bf16 GEMM, C = A[M,K] @ B[N,K]^T + bias (fp32 out), m97-ladder structure ----
// 128x128 tile, BK=32, 4 waves, each wave 4x4 of 16x16x32 MFMA.
__global__ __launch_bounds__(256) void gemm_bt(
    const unsigned short* __restrict__ A, const unsigned short* __restrict__ B,
    const float* __restrict__ bias, float* __restrict__ C,
    int M, int N, int K)
{
    __shared__ unsigned short sA[128 * 32];   // 8 KB, row-major [128][32], no pad (global_load_lds)
    __shared__ unsigned short sB[128 * 32];

    int tid = threadIdx.x;
    int w = tid >> 6, l = tid & 63;
    int bm = blockIdx.y, bn = blockIdx.x;
    int wm = (w >> 1) * 64, wn = (w & 1) * 64;
    int quad = l >> 4, lane16 = l & 15;

    floatx4 acc[4][4] = {};

    const unsigned short* Ag = A + (size_t)(bm * 128) * K;
    const unsigned short* Bg = B + (size_t)(bn * 128) * K;

    for (int kt = 0; kt < K; kt += 32) {
        // stage 512 chunks (16B each) per tile; chunk c = w*128 + j*64 + lane
        #pragma unroll
        for (int j = 0; j < 2; j++) {
            int c = w * 128 + j * 64 + l;
            int row = c >> 2, col = (c & 3) * 8;
            __builtin_amdgcn_global_load_lds(
                (const AS_G void*)(Ag + (size_t)row * K + kt + col),
                (AS_L void*)(sA + (w * 128 + j * 64) * 8), 16, 0, 0);
            __builtin_amdgcn_global_load_lds(
                (const AS_G void*)(Bg + (size_t)row * K + kt + col),
                (AS_L void*)(sB + (w * 128 + j * 64) * 8), 16, 0, 0);
        }
        __syncthreads();

        short8 af[4], bf[4];
        #pragma unroll
        for (int i = 0; i < 4; i++)
            af[i] = *(const short8*)(sA + (wm + i * 16 + lane16) * 32 + quad * 8);
        #pragma unroll
        for (int j = 0; j < 4; j++)
            bf[j] = *(const short8*)(sB + (wn + j * 16 + lane16) * 32 + quad * 8);
        #pragma unroll
        for (int i = 0; i < 4; i++)
            #pragma unroll
            for (int j = 0; j < 4; j++)
                acc[i][j] = __builtin_amdgcn_mfma_f32_16x16x32_bf16(af[i], bf[j], acc[i][j], 0, 0, 0);
        __syncthreads();
    }

    // epilogue: C/D layout col = lane&15, row = quad*4 + reg (m89/m91-verified). fp32 store.
    #pragma unroll
    for (int i = 0; i < 4; i++) {
        int row = bm * 128 + wm + i * 16 + quad * 4;
        #pragma unroll
        for (int j = 0; j < 4; j++) {
            int col = bn * 128 + wn + j * 16 + lane16;
            float bv = bias[col];
            #pragma unroll
            for (int r = 0; r < 4; r++) {
                C[(size_t)(row + r) * N + col] = acc[i][j][r] + bv;
            }
        }
    }
}

extern "C" void kernel_launch(void* const* d_in, const int* in_sizes, int n_in,
                              void* d_out, int out_size, void* d_ws, size_t ws_size,
                              hipStream_t stream) {
    const int* AN   = (const int*)d_in[0];
    const int* AS_  = (const int*)d_in[1];
    const int* AO   = (const int*)d_in[2];
    const int* SFAN = (const int*)d_in[3];
    const int* SFAS = (const int*)d_in[4];
    const int* SFAO = (const int*)d_in[5];
    const int* BN   = (const int*)d_in[6];
    const int* BS   = (const int*)d_in[7];
    const int* BO   = (const int*)d_in[8];
    const int* SFBN = (const int*)d_in[9];
    const int* SFBS = (const int*)d_in[10];
    const int* SFBO = (const int*)d_in[11];
    const float* bias = (const float*)d_in[12];

    int M = in_sizes[0] / 1536;   // p4/2 = 1536 int32 per row
    int N = in_sizes[6] / 1536;
    const int K = 4096;           // 3072 fp4 + 768 fp6 + 256 fp8

    unsigned short* Adq = (unsigned short*)d_ws;
    unsigned short* Bdq = Adq + (size_t)M * K;

    dequant_kernel<<<(M * 512 + 255) / 256, 256, 0, stream>>>(AN, AS_, AO, SFAN, SFAS, SFAO, Adq, M);
    dequant_kernel<<<(N * 512 + 255) / 256, 256, 0, stream>>>(BN, BS, BO, SFBN, SFBS, SFBO, Bdq, N);

    dim3 grid(N / 128, M / 128);
    gemm_bt<<<grid, 256, 0, stream>>>(Adq, Bdq, bias, (float*)d_out, M, N, K);
}

// Round 3
// 267.675 us; speedup vs baseline: 1.3223x; 1.3223x over previous
//
#include <hip/hip_runtime.h>
#include <hip/hip_bf16.h>

typedef short short8 __attribute__((ext_vector_type(8)));
typedef int   intx8  __attribute__((ext_vector_type(8)));
typedef float floatx16 __attribute__((ext_vector_type(16)));

#define AS_G __attribute__((address_space(1)))
#define AS_L __attribute__((address_space(3)))

__device__ __forceinline__ unsigned short f2bf(float f) {
    union { float f; unsigned u; } v; v.f = f;
    unsigned r = (v.u + 0x7FFF + ((v.u >> 16) & 1)) >> 16;
    return (unsigned short)r;
}

__device__ __forceinline__ float dec8(int c) {          // E4M3, bias 7 (NaN code -> 480, like ref)
    float s = (c & 128) ? -1.f : 1.f;
    int e = (c >> 3) & 15, m = c & 7;
    float mag = e ? ldexpf(1.f + 0.125f * (float)m, e - 7) : ldexpf(0.125f * (float)m, -6);
    return s * mag;
}

// ---- prepass (one per side): byte-pack fp4/fp6 codes, decode fp8->bf16 (scaled),
// ---- transpose fp4/fp6 scales to [kb][row] bytes for coalesced GEMM loads.
__global__ __launch_bounds__(256) void pack_side(
    const int* __restrict__ Pn, const int* __restrict__ Ps, const int* __restrict__ Po,
    const int* __restrict__ Sn, const int* __restrict__ Ss, const int* __restrict__ So,
    unsigned char* __restrict__ c4, unsigned char* __restrict__ c6,
    unsigned short* __restrict__ d8,
    unsigned char* __restrict__ s4t, unsigned char* __restrict__ s6t, int R)
{
    int t = blockIdx.x * 256 + threadIdx.x;
    int T0 = R * 96, T1 = T0 + R * 36, T2 = T1 + R * 32, T3 = T2 + R * 24, T4 = T3 + R * 6;
    if (t < T0) {                                   // fp4 pack: 16 bytes from 16 int32
        int r = t / 96, j = t % 96;
        const int4* p = (const int4*)(Pn + (size_t)r * 1536 + j * 16);
        uint4 o; unsigned* po = (unsigned*)&o;
        #pragma unroll
        for (int q = 0; q < 4; q++) {
            int4 b = p[q];
            po[q] = (b.x & 255) | ((b.y & 255) << 8) | ((b.z & 255) << 16) | ((unsigned)(b.w & 255) << 24);
        }
        *(uint4*)(c4 + (size_t)r * 1536 + j * 16) = o;
    } else if (t < T1) {                            // fp6 pack
        t -= T0; int r = t / 36, j = t % 36;
        const int4* p = (const int4*)(Ps + (size_t)r * 576 + j * 16);
        uint4 o; unsigned* po = (unsigned*)&o;
        #pragma unroll
        for (int q = 0; q < 4; q++) {
            int4 b = p[q];
            po[q] = (b.x & 255) | ((b.y & 255) << 8) | ((b.z & 255) << 16) | ((unsigned)(b.w & 255) << 24);
        }
        *(uint4*)(c6 + (size_t)r * 576 + j * 16) = o;
    } else if (t < T2) {                            // fp8 -> scaled bf16 (8 elems/thread)
        t -= T1; int r = t / 32, j = t % 32;
        const int4* p = (const int4*)(Po + (size_t)r * 256 + j * 8);
        int4 c0 = p[0], c1 = p[1];
        int e = So[r * 8 + (j >> 2)] - 127;
        int cs[8] = { c0.x, c0.y, c0.z, c0.w, c1.x, c1.y, c1.z, c1.w };
        uint4 o; unsigned* po = (unsigned*)&o;
        #pragma unroll
        for (int i = 0; i < 4; i++) {
            unsigned lo = f2bf(ldexpf(dec8(cs[2 * i] & 255), e));
            unsigned hi = f2bf(ldexpf(dec8(cs[2 * i + 1] & 255), e));
            po[i] = lo | (hi << 16);
        }
        *(uint4*)(d8 + (size_t)r * 256 + j * 8) = o;
    } else if (t < T3) {                            // fp4 scale transpose: s4t[kb][r]
        t -= T2; int RQ = R >> 2;
        int kb = t / RQ, rq = t - kb * RQ, r0 = rq * 4;
        unsigned o = 0;
        #pragma unroll
        for (int i = 0; i < 4; i++)
            o |= (unsigned)(Sn[(size_t)(r0 + i) * 96 + kb] & 255) << (8 * i);
        *(unsigned*)(s4t + (size_t)kb * R + r0) = o;
    } else if (t < T4) {                            // fp6 scale transpose: s6t[kb][r]
        t -= T3; int RQ = R >> 2;
        int kb = t / RQ, rq = t - kb * RQ, r0 = rq * 4;
        unsigned o = 0;
        #pragma unroll
        for (int i = 0; i < 4; i++)
            o |= (unsigned)(Ss[(size_t)(r0 + i) * 24 + kb] & 255) << (8 * i);
        *(unsigned*)(s6t + (size_t)kb * R + r0) = o;
    }
}

// ---- fused MX GEMM: C = sum over {fp4 MX, fp6(bf6) MX, fp8-as-bf16} + bias, fp32 out.
// 128x128 tile, 4 waves, each wave 2x2 of 32x32 accumulators (shared across segments:
// C/D layout is shape-determined, dtype-independent). LDS: k-major 16B blocks,
// lds_off = kb16*2048 + row*16 (wave-uniform global_load_lds staging, <=4-way bank alias).
__global__ __launch_bounds__(256) void gemm_mx(
    const unsigned char* __restrict__ A4, const unsigned char* __restrict__ B4,
    const unsigned char* __restrict__ A6, const unsigned char* __restrict__ B6,
    const unsigned short* __restrict__ A8, const unsigned short* __restrict__ B8,
    const unsigned char* __restrict__ Sa4, const unsigned char* __restrict__ Sb4,
    const unsigned char* __restrict__ Sa6, const unsigned char* __restrict__ Sb6,
    const float* __restrict__ bias, float* __restrict__ C, int M, int N)
{
    __shared__ __align__(16) unsigned char sA[16384];
    __shared__ __align__(16) unsigned char sB[16384];

    int tid = threadIdx.x, w = tid >> 6, l = tid & 63;
    int bm = blockIdx.y, bn = blockIdx.x;
    int wm = (w >> 1) * 64, wn = (w & 1) * 64;
    int lr = l & 31, lh = l >> 5;

    floatx16 acc[2][2] = {};

    int rgA[2] = { bm * 128 + wm + lr, bm * 128 + wm + 32 + lr };  // global A rows of my frags
    int cgB[2] = { bn * 128 + wn + lr, bn * 128 + wn + 32 + lr };  // global B cols

    // ================= fp4 segment: K=3072, BK=128 (64 B/row, 4 subs) =================
    for (int kt = 0; kt < 3072; kt += 128) {
        #pragma unroll
        for (int j = 0; j < 2; j++) {
            int bc = j * 256 + w * 64;                 // wave-uniform chunk base
            int c = bc + l;
            int sub = c >> 7, row = c & 127;
            __builtin_amdgcn_global_load_lds(
                (const AS_G void*)(A4 + (size_t)(bm * 128 + row) * 1536 + (kt >> 1) + sub * 16),
                (AS_L void*)(sA + bc * 16), 16, 0, 0);
            __builtin_amdgcn_global_load_lds(
                (const AS_G void*)(B4 + (size_t)(bn * 128 + row) * 1536 + (kt >> 1) + sub * 16),
                (AS_L void*)(sB + bc * 16), 16, 0, 0);
        }
        __syncthreads();
        #pragma unroll
        for (int s = 0; s < 2; s++) {
            int kb16 = s * 2 + lh;                     // 16B block = one 32-elem k-block
            size_t kbg = (size_t)((kt >> 5) + kb16);
            intx8 af[2], bf2[2]; int sa[2], sb[2];
            #pragma unroll
            for (int i = 0; i < 2; i++) {
                int4 v = *(const int4*)(sA + kb16 * 2048 + (wm + i * 32 + lr) * 16);
                af[i] = (intx8){ v.x, v.y, v.z, v.w, 0, 0, 0, 0 };
                sa[i] = Sa4[kbg * M + rgA[i]];
            }
            #pragma unroll
            for (int j = 0; j < 2; j++) {
                int4 v = *(const int4*)(sB + kb16 * 2048 + (wn + j * 32 + lr) * 16);
                bf2[j] = (intx8){ v.x, v.y, v.z, v.w, 0, 0, 0, 0 };
                sb[j] = Sb4[kbg * N + cgB[j]];
            }
            #pragma unroll
            for (int i = 0; i < 2; i++)
                #pragma unroll
                for (int j = 0; j < 2; j++)
                    acc[i][j] = __builtin_amdgcn_mfma_scale_f32_32x32x64_f8f6f4(
                        af[i], bf2[j], acc[i][j], 4, 4, 0, sa[i], 0, sb[j]);   // fmt 4 = E2M1 fp4
        }
        __syncthreads();
    }

    // ================= fp6 (E3M2 = bf6, fmt 3): K=768, BK=64 (48 B/row, 3 subs) =================
    for (int kt = 0; kt < 768; kt += 64) {
        {
            int bc = w * 64, c = bc + l;
            int sub = c >> 7, row = c & 127;
            __builtin_amdgcn_global_load_lds(
                (const AS_G void*)(A6 + (size_t)(bm * 128 + row) * 576 + (kt >> 6) * 48 + sub * 16),
                (AS_L void*)(sA + bc * 16), 16, 0, 0);
            __builtin_amdgcn_global_load_lds(
                (const AS_G void*)(B6 + (size_t)(bn * 128 + row) * 576 + (kt >> 6) * 48 + sub * 16),
                (AS_L void*)(sB + bc * 16), 16, 0, 0);
        }
        if (w < 2) {
            int bc = 256 + w * 64, c = bc + l;
            int sub = c >> 7, row = c & 127;
            __builtin_amdgcn_global_load_lds(
                (const AS_G void*)(A6 + (size_t)(bm * 128 + row) * 576 + (kt >> 6) * 48 + sub * 16),
                (AS_L void*)(sA + bc * 16), 16, 0, 0);
            __builtin_amdgcn_global_load_lds(
                (const AS_G void*)(B6 + (size_t)(bn * 128 + row) * 576 + (kt >> 6) * 48 + sub * 16),
                (AS_L void*)(sB + bc * 16), 16, 0, 0);
        }
        __syncthreads();
        {
            size_t kbg = (size_t)((kt >> 5) + lh);
            intx8 af[2], bf2[2]; int sa[2], sb[2];
            #pragma unroll
            for (int i = 0; i < 2; i++) {
                int r16 = (wm + i * 32 + lr) * 16;
                int4 v = *(const int4*)(sA + lh * 4096 + r16);        // b128 part
                int2 u = *(const int2*)(sA + 2048 + r16 + lh * 8);    // b64 part
                // kb0: bytes[0..24) = v,u ; kb1: bytes[24..48) = u,v  (6-bit LE pack, v[0:5])
                af[i] = (intx8){ lh ? u.x : v.x, lh ? u.y : v.y, lh ? v.x : v.z,
                                 lh ? v.y : v.w, lh ? v.z : u.x, lh ? v.w : u.y, 0, 0 };
                sa[i] = Sa6[kbg * M + rgA[i]];
            }
            #pragma unroll
            for (int j = 0; j < 2; j++) {
                int r16 = (wn + j * 32 + lr) * 16;
                int4 v = *(const int4*)(sB + lh * 4096 + r16);
                int2 u = *(const int2*)(sB + 2048 + r16 + lh * 8);
                bf2[j] = (intx8){ lh ? u.x : v.x, lh ? u.y : v.y, lh ? v.x : v.z,
                                  lh ? v.y : v.w, lh ? v.z : u.x, lh ? v.w : u.y, 0, 0 };
                sb[j] = Sb6[kbg * N + cgB[j]];
            }
            #pragma unroll
            for (int i = 0; i < 2; i++)
                #pragma unroll
                for (int j = 0; j < 2; j++)
                    acc[i][j] = __builtin_amdgcn_mfma_scale_f32_32x32x64_f8f6f4(
                        af[i], bf2[j], acc[i][j], 3, 3, 0, sa[i], 0, sb[j]);   // fmt 3 = E3M2 bf6
        }
        __syncthreads();
    }

    // ================= fp8 segment as bf16: K=256, BK=64 (128 B/row, 8 subs) =================
    for (int kt = 0; kt < 256; kt += 64) {
        #pragma unroll
        for (int j = 0; j < 4; j++) {
            int bc = j * 256 + w * 64, c = bc + l;
            int sub = c >> 7, row = c & 127;
            __builtin_amdgcn_global_load_lds(
                (const AS_G void*)((const unsigned char*)A8 + (size_t)(bm * 128 + row) * 512 + kt * 2 + sub * 16),
                (AS_L void*)(sA + bc * 16), 16, 0, 0);
            __builtin_amdgcn_global_load_lds(
                (const AS_G void*)((const unsigned char*)B8 + (size_t)(bn * 128 + row) * 512 + kt * 2 + sub * 16),
                (AS_L void*)(sB + bc * 16), 16, 0, 0);
        }
        __syncthreads();
        #pragma unroll
        for (int s = 0; s < 4; s++) {
            int kb16 = s * 2 + lh;
            short8 af[2], bf2[2];
            #pragma unroll
            for (int i = 0; i < 2; i++)
                af[i] = *(const short8*)(sA + kb16 * 2048 + (wm + i * 32 + lr) * 16);
            #pragma unroll
            for (int j = 0; j < 2; j++)
                bf2[j] = *(const short8*)(sB + kb16 * 2048 + (wn + j * 32 + lr) * 16);
            #pragma unroll
            for (int i = 0; i < 2; i++)
                #pragma unroll
                for (int j = 0; j < 2; j++)
                    acc[i][j] = __builtin_amdgcn_mfma_f32_32x32x16_bf16(af[i], bf2[j], acc[i][j], 0, 0, 0);
        }
        __syncthreads();
    }

    // epilogue: 32x32 C/D layout col=lane&31, row=(r&3)+8*(r>>2)+4*lh (m74/m101-verified)
    #pragma unroll
    for (int i = 0; i < 2; i++)
        #pragma unroll
        for (int j = 0; j < 2; j++) {
            int col = bn * 128 + wn + j * 32 + lr;
            float bv = bias[col];
            #pragma unroll
            for (int r = 0; r < 16; r++) {
                int row = bm * 128 + wm + i * 32 + (r & 3) + 8 * (r >> 2) + 4 * lh;
                C[(size_t)row * N + col] = acc[i][j][r] + bv;
            }
        }
}

extern "C" void kernel_launch(void* const* d_in, const int* in_sizes, int n_in,
                              void* d_out, int out_size, void* d_ws, size_t ws_size,
                              hipStream_t stream) {
    const int* AN   = (const int*)d_in[0];
    const int* ASs  = (const int*)d_in[1];
    const int* AO   = (const int*)d_in[2];
    const int* SFAN = (const int*)d_in[3];
    const int* SFAS = (const int*)d_in[4];
    const int* SFAO = (const int*)d_in[5];
    const int* BN   = (const int*)d_in[6];
    const int* BS   = (const int*)d_in[7];
    const int* BO   = (const int*)d_in[8];
    const int* SFBN = (const int*)d_in[9];
    const int* SFBS = (const int*)d_in[10];
    const int* SFBO = (const int*)d_in[11];
    const float* bias = (const float*)d_in[12];

    int M = in_sizes[0] / 1536;
    int N = in_sizes[6] / 1536;

    unsigned char* ws = (unsigned char*)d_ws;
    size_t o = 0;
    unsigned char* A4c = ws + o;            o += (size_t)M * 1536;
    unsigned char* B4c = ws + o;            o += (size_t)N * 1536;
    unsigned char* A6c = ws + o;            o += (size_t)M * 576;
    unsigned char* B6c = ws + o;            o += (size_t)N * 576;
    unsigned short* A8d = (unsigned short*)(ws + o); o += (size_t)M * 512;
    unsigned short* B8d = (unsigned short*)(ws + o); o += (size_t)N * 512;
    unsigned char* Sa4t = ws + o;           o += (size_t)96 * M;
    unsigned char* Sb4t = ws + o;           o += (size_t)96 * N;
    unsigned char* Sa6t = ws + o;           o += (size_t)24 * M;
    unsigned char* Sb6t = ws + o;           o += (size_t)24 * N;

    int TA = M * 194, TB = N * 194;
    pack_side<<<(TA + 255) / 256, 256, 0, stream>>>(AN, ASs, AO, SFAN, SFAS, SFAO,
                                                    A4c, A6c, A8d, Sa4t, Sa6t, M);
    pack_side<<<(TB + 255) / 256, 256, 0, stream>>>(BN, BS, BO, SFBN, SFBS, SFBO,
                                                    B4c, B6c, B8d, Sb4t, Sb6t, N);

    dim3 grid(N / 128, M / 128);
    gemm_mx<<<grid, 256, 0, stream>>>(A4c, B4c, A6c, B6c, A8d, B8d,
                                      Sa4t, Sb4t, Sa6t, Sb6t, bias, (float*)d_out, M, N);
}